// Round 3
// baseline (428.573 us; speedup 1.0000x reference)
//
#include <hip/hip_runtime.h>
#include <hip/hip_bf16.h>

typedef __bf16 bf16x8 __attribute__((ext_vector_type(8)));
typedef float  f32x4  __attribute__((ext_vector_type(4)));

#define BATCH 2
#define SEQ   2048
#define HID   2048
#define NH    8
#define DH    256
#define LQ    2560            // QKV row: 8*256 Q + 256 K + 256 V
#define ROWS  (BATCH*SEQ)     // 4096
#define KVB   32

__device__ __forceinline__ void gld16(const void* g, void* l) {
    __builtin_amdgcn_global_load_lds(
        (__attribute__((address_space(1))) void*)(g),
        (__attribute__((address_space(3))) void*)(l), 16, 0, 0);
}

__device__ __forceinline__ unsigned pack2bf(float a, float b) {
    union { __bf16 h[2]; unsigned u; } x;
    x.h[0] = (__bf16)a; x.h[1] = (__bf16)b;
    return x.u;
}

// ---------------- fp32 -> bf16 convert (vectorized) ----------------
__global__ void cvt_f32_bf16(const float* __restrict__ src, __bf16* __restrict__ dst, int n4) {
    int i = blockIdx.x * blockDim.x + threadIdx.x;
    if (i < n4) {
        float4 v = ((const float4*)src)[i];
        __bf16 o[4];
        o[0] = (__bf16)v.x; o[1] = (__bf16)v.y; o[2] = (__bf16)v.z; o[3] = (__bf16)v.w;
        ((uint2*)dst)[i] = *(uint2*)o;
    }
}

// ---------------- GEMM: C[M][N] = A[M][K] * B[N][K]^T (bf16 in, CT out) ----------------
template<typename CT>
__global__ __launch_bounds__(256)
void gemm_bt(const __bf16* __restrict__ A, const __bf16* __restrict__ B,
             CT* __restrict__ C, int M, int N, int K) {
    __shared__ __bf16 sA[128 * 32];
    __shared__ __bf16 sB[128 * 32];
    const int tid  = threadIdx.x;
    const int lane = tid & 63;
    const int wid  = tid >> 6;
    const int row0 = blockIdx.y * 128;
    const int col0 = blockIdx.x * 128;
    const int wr = (wid >> 1) * 64;
    const int wc = (wid & 1) * 64;

    const int sr0 = tid >> 2, sc0 = (tid & 3) * 8;
    const __bf16* Ag0 = A + (size_t)(row0 + sr0) * K + sc0;
    const __bf16* Ag1 = Ag0 + (size_t)64 * K;
    const __bf16* Bg0 = B + (size_t)(col0 + sr0) * K + sc0;
    const __bf16* Bg1 = Bg0 + (size_t)64 * K;
    __bf16* lA0 = &sA[wid * 512];
    __bf16* lA1 = &sA[2048 + wid * 512];
    __bf16* lB0 = &sB[wid * 512];
    __bf16* lB1 = &sB[2048 + wid * 512];

    f32x4 acc[4][4];
#pragma unroll
    for (int m = 0; m < 4; ++m)
#pragma unroll
        for (int n = 0; n < 4; ++n) acc[m][n] = (f32x4)0.f;

    for (int k0 = 0; k0 < K; k0 += 32) {
        gld16(Ag0 + k0, lA0);
        gld16(Ag1 + k0, lA1);
        gld16(Bg0 + k0, lB0);
        gld16(Bg1 + k0, lB1);
        __syncthreads();
        bf16x8 af[4], bfr[4];
#pragma unroll
        for (int m = 0; m < 4; ++m)
            af[m] = *(const bf16x8*)&sA[(wr + m * 16 + (lane & 15)) * 32 + (lane >> 4) * 8];
#pragma unroll
        for (int n = 0; n < 4; ++n)
            bfr[n] = *(const bf16x8*)&sB[(wc + n * 16 + (lane & 15)) * 32 + (lane >> 4) * 8];
#pragma unroll
        for (int m = 0; m < 4; ++m)
#pragma unroll
            for (int n = 0; n < 4; ++n)
                acc[m][n] = __builtin_amdgcn_mfma_f32_16x16x32_bf16(af[m], bfr[n], acc[m][n], 0, 0, 0);
        __syncthreads();
    }
#pragma unroll
    for (int m = 0; m < 4; ++m)
#pragma unroll
        for (int n = 0; n < 4; ++n)
#pragma unroll
            for (int r = 0; r < 4; ++r) {
                int row = row0 + wr + m * 16 + (lane >> 4) * 4 + r;
                int col = col0 + wc + n * 16 + (lane & 15);
                C[(size_t)row * N + col] = (CT)acc[m][n][r];
            }
}

// ---------------- RoPE in-place on QKV (heads 0..7 = Q scaled by 1/16, head 8 = K) --------
__global__ void rope_kernel(__bf16* __restrict__ QKV, const int* __restrict__ pid) {
    const int row = blockIdx.x;   // 0..4095
    const int h   = blockIdx.y;   // 0..8
    const int j   = threadIdx.x;  // 0..127
    const float pos = (float)pid[row];
    const float freq = exp2f((float)j * (-13.287712379549449f / 128.0f));
    const float ang = pos * freq;
    float sn, cs;
    sincosf(ang, &sn, &cs);
    const float sc = (h < 8) ? 0.0625f : 1.0f;   // fold 1/sqrt(256) into Q
    __bf16* p = QKV + (size_t)row * LQ + h * 256 + j;
    float x1 = (float)p[0], x2 = (float)p[128];
    p[0]   = (__bf16)((x1 * cs - x2 * sn) * sc);
    p[128] = (__bf16)((x2 * cs + x1 * sn) * sc);
}

// ---------------- V transpose: QKV cols 2304.. -> Vt[B][256][SEQ] ----------------
__global__ __launch_bounds__(256)
void transpose_v(const __bf16* __restrict__ QKV, __bf16* __restrict__ Vt) {
    __shared__ __bf16 t[32][33];
    const int b  = blockIdx.z;
    const int s0 = blockIdx.x * 32;
    const int d0 = blockIdx.y * 32;
    const int c  = threadIdx.x & 31;
    const int r8 = threadIdx.x >> 5;
#pragma unroll
    for (int i = 0; i < 4; ++i) {
        int row = r8 + i * 8;
        t[row][c] = QKV[(size_t)(b * SEQ + s0 + row) * LQ + 2304 + d0 + c];
    }
    __syncthreads();
#pragma unroll
    for (int i = 0; i < 4; ++i) {
        int row = r8 + i * 8;
        Vt[((size_t)b * 256 + d0 + row) * SEQ + s0 + c] = t[c][row];
    }
}

// ---------------- Flash attention v3 ----------------
// 512 blocks x 128 thr (2 waves = 2 heads). Each wave: 32 q rows (chunk qt), nt=qt+1
// kv tiles of 32. Complementary pairing: bid & bid+256 get qt and 63-qt so co-resident
// blocks sum to uniform work. K/V dbuf in LDS (gld16 w16, K ^(r&7)<<4, V ^((d>>1)&3)<<4).
// Swapped QK^T -> lane-local softmax with defer-max; P^T to PV B-frag via pack+shfl.
__global__ __launch_bounds__(128, 1)
void attn_fwd3(const __bf16* __restrict__ QKV, const __bf16* __restrict__ Vt,
               __bf16* __restrict__ O) {
    __shared__ __bf16 Kt[2][KVB * 256];   // [kv][256d], col-bytes ^= (kv&7)<<4
    __shared__ __bf16 Vs[2][256 * KVB];   // [d][32kv],  col-bytes ^= ((d>>1)&3)<<4

    const int tid  = threadIdx.x;
    const int lane = tid & 63;
    const int wid  = tid >> 6;          // 0..1
    const int lc   = lane & 15;
    const int l4   = lane >> 4;

    const int bid = blockIdx.x;
    int qt, b, hg;
    if (bid < 256) { qt = bid & 63;        b = (bid >> 6) & 1; hg = (bid >> 7) & 1; }
    else { int r = bid - 256; qt = 63 - (r & 63); b = (r >> 6) & 1; hg = 2 + ((r >> 7) & 1); }
    const int h  = hg * 2 + wid;
    const int q0 = qt * 32;
    const int nt = qt + 1;

    const char* QKVb = (const char*)(QKV + (size_t)(b * SEQ) * LQ);
    const char* Kg   = QKVb + 2048 * 2;
    const char* Vg   = (const char*)(Vt + (size_t)b * DH * SEQ);

    // staging constants
    const int krow = wid * 16 + (lane >> 5);            // + i*2
    const int kcol = (lane & 31) * 16;
    const int vrow = wid * 128 + (lane >> 2);           // + i*16
    const int vcol = ((lane & 3) * 16) ^ (((vrow >> 1) & 3) << 4);
    const int vrsw = ((lc >> 1) & 3) << 4;              // V read swizzle

    // Q fragments, 2 q-sets: col q = q0 + qs*16 + lc, k(d) = l4*8 + kc*32
    bf16x8 qf[2][8];
#pragma unroll
    for (int qs = 0; qs < 2; ++qs) {
        const char* Qp = QKVb + (size_t)(q0 + qs * 16 + lc) * (LQ * 2) + h * 512 + l4 * 16;
#pragma unroll
        for (int kc = 0; kc < 8; ++kc) qf[qs][kc] = *(const bf16x8*)(Qp + kc * 64);
    }

    f32x4 oacc[2][16];
#pragma unroll
    for (int qs = 0; qs < 2; ++qs)
#pragma unroll
        for (int i = 0; i < 16; ++i) oacc[qs][i] = (f32x4)0.f;
    float mrow[2] = {-1e30f, -1e30f}, lrow[2] = {0.f, 0.f};

    // prologue: stage tile 0 into buf 0
#pragma unroll
    for (int i = 0; i < 8; ++i) {
        int r = krow + i * 2;
        gld16(Kg + (size_t)r * (LQ * 2) + (kcol ^ ((r & 7) << 4)),
              (char*)&Kt[0][0] + wid * 8192 + i * 1024);
    }
#pragma unroll
    for (int i = 0; i < 8; ++i) {
        int r = vrow + i * 16;
        gld16(Vg + (size_t)r * (SEQ * 2) + vcol,
              (char*)&Vs[0][0] + wid * 8192 + i * 1024);
    }

    int buf = 0;
    for (int t = 0; t < nt; ++t) {
        __syncthreads();                       // stage for t complete (each wave drains own vmcnt)
        const int kv0 = t * KVB;
        if (t + 1 < nt) {                      // issue stage for t+1 into buf^1
            const int kvn = kv0 + KVB;
#pragma unroll
            for (int i = 0; i < 8; ++i) {
                int r = krow + i * 2;
                gld16(Kg + (size_t)(kvn + r) * (LQ * 2) + (kcol ^ ((r & 7) << 4)),
                      (char*)&Kt[buf ^ 1][0] + wid * 8192 + i * 1024);
            }
#pragma unroll
            for (int i = 0; i < 8; ++i) {
                int r = vrow + i * 16;
                gld16(Vg + (size_t)r * (SEQ * 2) + kvn * 2 + vcol,
                      (char*)&Vs[buf ^ 1][0] + wid * 8192 + i * 1024);
            }
        }

        // S^T = K * Q^T : rows kv (A=K), cols q (B=Q), both q-sets share kf
        f32x4 sacc[2][2];
        sacc[0][0] = (f32x4)0.f; sacc[0][1] = (f32x4)0.f;
        sacc[1][0] = (f32x4)0.f; sacc[1][1] = (f32x4)0.f;
        const char* Kl = (const char*)&Kt[buf][0];
        __builtin_amdgcn_s_setprio(1);
#pragma unroll
        for (int ct = 0; ct < 2; ++ct) {
            const int rr = ct * 16 + lc;
            const int rbase = rr * 512;
            const int sw = (rr & 7) << 4;
#pragma unroll
            for (int kc = 0; kc < 8; ++kc) {
                bf16x8 kf = *(const bf16x8*)(Kl + rbase + (((kc << 6) | (l4 << 4)) ^ sw));
                sacc[0][ct] = __builtin_amdgcn_mfma_f32_16x16x32_bf16(kf, qf[0][kc], sacc[0][ct], 0, 0, 0);
                sacc[1][ct] = __builtin_amdgcn_mfma_f32_16x16x32_bf16(kf, qf[1][kc], sacc[1][ct], 0, 0, 0);
            }
        }
        __builtin_amdgcn_s_setprio(0);

        // online softmax (deferred max, THR=8), per q-set; scores pre-scaled via Q
        const bool lastt = (t == nt - 1);
        bf16x8 pbv[2];
#pragma unroll
        for (int qs = 0; qs < 2; ++qs) {
            const int qrow = q0 + qs * 16 + lc;
            float tm = -1e30f;
#pragma unroll
            for (int ct = 0; ct < 2; ++ct)
#pragma unroll
                for (int r = 0; r < 4; ++r) {
                    float s = sacc[qs][ct][r];
                    if (lastt) {
                        int kv = kv0 + ct * 16 + l4 * 4 + r;
                        if (kv > qrow) s = -1e30f;
                    }
                    sacc[qs][ct][r] = s;
                    tm = fmaxf(tm, s);
                }
            tm = fmaxf(tm, __shfl_xor(tm, 16, 64));
            tm = fmaxf(tm, __shfl_xor(tm, 32, 64));
            if (!__all(tm <= mrow[qs] + 8.f)) {
                const float mnew  = fmaxf(mrow[qs], tm);
                const float alpha = __expf(mrow[qs] - mnew);
                mrow[qs] = mnew;
                lrow[qs] *= alpha;
#pragma unroll
                for (int dt = 0; dt < 16; ++dt) {
                    oacc[qs][dt][0] *= alpha; oacc[qs][dt][1] *= alpha;
                    oacc[qs][dt][2] *= alpha; oacc[qs][dt][3] *= alpha;
                }
            }
            float p0[4], p1[4], ps = 0.f;
#pragma unroll
            for (int r = 0; r < 4; ++r) { p0[r] = __expf(sacc[qs][0][r] - mrow[qs]); ps += p0[r]; }
#pragma unroll
            for (int r = 0; r < 4; ++r) { p1[r] = __expf(sacc[qs][1][r] - mrow[qs]); ps += p1[r]; }
            ps += __shfl_xor(ps, 16, 64);
            ps += __shfl_xor(ps, 32, 64);
            lrow[qs] += ps;

            // P^T -> PV B-frag: lane needs kv = l4*8+j at q = lc
            unsigned pkA0 = pack2bf(p0[0], p0[1]), pkA1 = pack2bf(p0[2], p0[3]);
            unsigned pkB0 = pack2bf(p1[0], p1[1]), pkB1 = pack2bf(p1[2], p1[3]);
            const int sl0 = lc + 16 * ((2 * l4) & 3);
            const int sl1 = lc + 16 * ((2 * l4 + 1) & 3);
            unsigned a0 = __shfl(pkA0, sl0, 64), a1 = __shfl(pkA1, sl0, 64);
            unsigned b0 = __shfl(pkB0, sl0, 64), b1 = __shfl(pkB1, sl0, 64);
            unsigned c0 = __shfl(pkA0, sl1, 64), c1 = __shfl(pkA1, sl1, 64);
            unsigned d0 = __shfl(pkB0, sl1, 64), d1 = __shfl(pkB1, sl1, 64);
            const bool hi = (l4 >= 2);
            union { unsigned u[4]; bf16x8 v; } pb;
            pb.u[0] = hi ? b0 : a0;
            pb.u[1] = hi ? b1 : a1;
            pb.u[2] = hi ? d0 : c0;
            pb.u[3] = hi ? d1 : c1;
            pbv[qs] = pb.v;
        }

        // O^T += V^T * P^T : rows d (A=V^T), cols q; both q-sets share vf
        const char* Vl = (const char*)&Vs[buf][0];
        __builtin_amdgcn_s_setprio(1);
#pragma unroll
        for (int dt = 0; dt < 16; ++dt) {
            bf16x8 vf = *(const bf16x8*)(Vl + (dt * 16 + lc) * 64 + ((l4 << 4) ^ vrsw));
            oacc[0][dt] = __builtin_amdgcn_mfma_f32_16x16x32_bf16(vf, pbv[0], oacc[0][dt], 0, 0, 0);
            oacc[1][dt] = __builtin_amdgcn_mfma_f32_16x16x32_bf16(vf, pbv[1], oacc[1][dt], 0, 0, 0);
        }
        __builtin_amdgcn_s_setprio(0);
        buf ^= 1;
    }

    // epilogue: normalize + store (lane q = lc, d = dt*16 + l4*4 + r)
#pragma unroll
    for (int qs = 0; qs < 2; ++qs) {
        const float inv = 1.f / lrow[qs];
        char* Op = (char*)O + ((size_t)(b * SEQ + q0 + qs * 16 + lc) * HID + h * 256 + l4 * 4) * 2;
#pragma unroll
        for (int dt = 0; dt < 16; ++dt) {
            __bf16 o4[4];
            o4[0] = (__bf16)(oacc[qs][dt][0] * inv);
            o4[1] = (__bf16)(oacc[qs][dt][1] * inv);
            o4[2] = (__bf16)(oacc[qs][dt][2] * inv);
            o4[3] = (__bf16)(oacc[qs][dt][3] * inv);
            *(uint2*)(Op + dt * 32) = *(uint2*)o4;
        }
    }
}

extern "C" void kernel_launch(void* const* d_in, const int* in_sizes, int n_in,
                              void* d_out, int out_size, void* d_ws, size_t ws_size,
                              hipStream_t stream) {
    const float* hs  = (const float*)d_in[0];
    const int*   pid = (const int*)d_in[1];
    const float* Wq  = (const float*)d_in[3];
    const float* Wk  = (const float*)d_in[4];
    const float* Wv  = (const float*)d_in[5];
    const float* Wo  = (const float*)d_in[6];
    float* out = (float*)d_out;

    char* ws = (char*)d_ws;
    __bf16* Xb   = (__bf16*)ws;                       ws += (size_t)ROWS * HID * 2;
    __bf16* Wqkv = (__bf16*)ws;                       ws += (size_t)LQ * HID * 2;
    __bf16* Wob  = (__bf16*)ws;                       ws += (size_t)HID * HID * 2;
    __bf16* QKV  = (__bf16*)ws;                       ws += (size_t)ROWS * LQ * 2;
    __bf16* Vt   = (__bf16*)ws;                       ws += (size_t)BATCH * DH * SEQ * 2;
    __bf16* Oat  = Xb;   // alias: X dead after QKV GEMM

    cvt_f32_bf16<<<(ROWS * HID / 4 + 255) / 256, 256, 0, stream>>>(hs, Xb, ROWS * HID / 4);
    cvt_f32_bf16<<<(HID * HID / 4 + 255) / 256, 256, 0, stream>>>(Wq, Wqkv, HID * HID / 4);
    cvt_f32_bf16<<<(DH * HID / 4 + 255) / 256, 256, 0, stream>>>(Wk, Wqkv + (size_t)2048 * HID, DH * HID / 4);
    cvt_f32_bf16<<<(DH * HID / 4 + 255) / 256, 256, 0, stream>>>(Wv, Wqkv + (size_t)2304 * HID, DH * HID / 4);
    cvt_f32_bf16<<<(HID * HID / 4 + 255) / 256, 256, 0, stream>>>(Wo, Wob, HID * HID / 4);

    gemm_bt<__bf16><<<dim3(LQ / 128, ROWS / 128), 256, 0, stream>>>(Xb, Wqkv, QKV, ROWS, LQ, HID);

    rope_kernel<<<dim3(ROWS, 9), 128, 0, stream>>>(QKV, pid);

    transpose_v<<<dim3(SEQ / 32, DH / 32, BATCH), 256, 0, stream>>>(QKV, Vt);

    attn_fwd3<<<dim3(512), 128, 0, stream>>>(QKV, Vt, Oat);

    gemm_bt<float><<<dim3(HID / 128, ROWS / 128), 256, 0, stream>>>(Oat, Wob, out, ROWS, HID, HID);
}

// Round 4
// 393.544 us; speedup vs baseline: 1.0890x; 1.0890x over previous
//
#include <hip/hip_runtime.h>
#include <hip/hip_bf16.h>

typedef __bf16 bf16x8 __attribute__((ext_vector_type(8)));
typedef float  f32x4  __attribute__((ext_vector_type(4)));

#define BATCH 2
#define SEQ   2048
#define HID   2048
#define NH    8
#define DH    256
#define LQ    2560            // QKV row: 8*256 Q + 256 K + 256 V
#define ROWS  (BATCH*SEQ)     // 4096
#define KVB   32

__device__ __forceinline__ void gld16(const void* g, void* l) {
    __builtin_amdgcn_global_load_lds(
        (__attribute__((address_space(1))) void*)(g),
        (__attribute__((address_space(3))) void*)(l), 16, 0, 0);
}

__device__ __forceinline__ unsigned pack2bf(float a, float b) {
    union { __bf16 h[2]; unsigned u; } x;
    x.h[0] = (__bf16)a; x.h[1] = (__bf16)b;
    return x.u;
}

// ---------------- fp32 -> bf16 convert (vectorized) ----------------
__global__ void cvt_f32_bf16(const float* __restrict__ src, __bf16* __restrict__ dst, int n4) {
    int i = blockIdx.x * blockDim.x + threadIdx.x;
    if (i < n4) {
        float4 v = ((const float4*)src)[i];
        __bf16 o[4];
        o[0] = (__bf16)v.x; o[1] = (__bf16)v.y; o[2] = (__bf16)v.z; o[3] = (__bf16)v.w;
        ((uint2*)dst)[i] = *(uint2*)o;
    }
}

// ---------------- GEMM: C[M][N] = A[M][K] * B[N][K]^T (bf16 in, CT out) ----------------
template<typename CT>
__global__ __launch_bounds__(256)
void gemm_bt(const __bf16* __restrict__ A, const __bf16* __restrict__ B,
             CT* __restrict__ C, int M, int N, int K) {
    __shared__ __bf16 sA[128 * 32];
    __shared__ __bf16 sB[128 * 32];
    const int tid  = threadIdx.x;
    const int lane = tid & 63;
    const int wid  = tid >> 6;
    const int row0 = blockIdx.y * 128;
    const int col0 = blockIdx.x * 128;
    const int wr = (wid >> 1) * 64;
    const int wc = (wid & 1) * 64;

    const int sr0 = tid >> 2, sc0 = (tid & 3) * 8;
    const __bf16* Ag0 = A + (size_t)(row0 + sr0) * K + sc0;
    const __bf16* Ag1 = Ag0 + (size_t)64 * K;
    const __bf16* Bg0 = B + (size_t)(col0 + sr0) * K + sc0;
    const __bf16* Bg1 = Bg0 + (size_t)64 * K;
    __bf16* lA0 = &sA[wid * 512];
    __bf16* lA1 = &sA[2048 + wid * 512];
    __bf16* lB0 = &sB[wid * 512];
    __bf16* lB1 = &sB[2048 + wid * 512];

    f32x4 acc[4][4];
#pragma unroll
    for (int m = 0; m < 4; ++m)
#pragma unroll
        for (int n = 0; n < 4; ++n) acc[m][n] = (f32x4)0.f;

    for (int k0 = 0; k0 < K; k0 += 32) {
        gld16(Ag0 + k0, lA0);
        gld16(Ag1 + k0, lA1);
        gld16(Bg0 + k0, lB0);
        gld16(Bg1 + k0, lB1);
        __syncthreads();
        bf16x8 af[4], bfr[4];
#pragma unroll
        for (int m = 0; m < 4; ++m)
            af[m] = *(const bf16x8*)&sA[(wr + m * 16 + (lane & 15)) * 32 + (lane >> 4) * 8];
#pragma unroll
        for (int n = 0; n < 4; ++n)
            bfr[n] = *(const bf16x8*)&sB[(wc + n * 16 + (lane & 15)) * 32 + (lane >> 4) * 8];
#pragma unroll
        for (int m = 0; m < 4; ++m)
#pragma unroll
            for (int n = 0; n < 4; ++n)
                acc[m][n] = __builtin_amdgcn_mfma_f32_16x16x32_bf16(af[m], bfr[n], acc[m][n], 0, 0, 0);
        __syncthreads();
    }
#pragma unroll
    for (int m = 0; m < 4; ++m)
#pragma unroll
        for (int n = 0; n < 4; ++n)
#pragma unroll
            for (int r = 0; r < 4; ++r) {
                int row = row0 + wr + m * 16 + (lane >> 4) * 4 + r;
                int col = col0 + wc + n * 16 + (lane & 15);
                C[(size_t)row * N + col] = (CT)acc[m][n][r];
            }
}

// ---------------- RoPE in-place on QKV (heads 0..7 = Q scaled by 1/16, head 8 = K) --------
__global__ void rope_kernel(__bf16* __restrict__ QKV, const int* __restrict__ pid) {
    const int row = blockIdx.x;   // 0..4095
    const int h   = blockIdx.y;   // 0..8
    const int j   = threadIdx.x;  // 0..127
    const float pos = (float)pid[row];
    const float freq = exp2f((float)j * (-13.287712379549449f / 128.0f));
    const float ang = pos * freq;
    float sn, cs;
    sincosf(ang, &sn, &cs);
    const float sc = (h < 8) ? 0.0625f : 1.0f;   // fold 1/sqrt(256) into Q
    __bf16* p = QKV + (size_t)row * LQ + h * 256 + j;
    float x1 = (float)p[0], x2 = (float)p[128];
    p[0]   = (__bf16)((x1 * cs - x2 * sn) * sc);
    p[128] = (__bf16)((x2 * cs + x1 * sn) * sc);
}

// ---------------- V transpose: QKV cols 2304.. -> Vt[B][256][SEQ] ----------------
__global__ __launch_bounds__(256)
void transpose_v(const __bf16* __restrict__ QKV, __bf16* __restrict__ Vt) {
    __shared__ __bf16 t[32][33];
    const int b  = blockIdx.z;
    const int s0 = blockIdx.x * 32;
    const int d0 = blockIdx.y * 32;
    const int c  = threadIdx.x & 31;
    const int r8 = threadIdx.x >> 5;
#pragma unroll
    for (int i = 0; i < 4; ++i) {
        int row = r8 + i * 8;
        t[row][c] = QKV[(size_t)(b * SEQ + s0 + row) * LQ + 2304 + d0 + c];
    }
    __syncthreads();
#pragma unroll
    for (int i = 0; i < 4; ++i) {
        int row = r8 + i * 8;
        Vt[((size_t)b * 256 + d0 + row) * SEQ + s0 + c] = t[c][row];
    }
}

// ---------------- Flash attention v4 ----------------
// 256 blocks x 512 thr (8 waves = 8 heads; GQA: all heads share K/V).
// Block (b, qt): 16 q-rows (chunk qt in [0,128)), each wave = one head's rows.
// nt = qt/2+1 kv tiles of 32. K/V double-buffered LDS, staged once per tile for
// all 8 heads (gld16 w16; K col ^= (kv&7)<<4, V col ^= ((d>>1)&3)<<4).
// Swapped QK^T -> lane-local softmax (defer-max THR=8); P^T via pack+shfl.
__global__ __launch_bounds__(512, 2)
void attn_fwd4(const __bf16* __restrict__ QKV, const __bf16* __restrict__ Vt,
               __bf16* __restrict__ O) {
    __shared__ __bf16 Kt[2][KVB * 256];   // [kv][256d], col-bytes ^= (kv&7)<<4
    __shared__ __bf16 Vs[2][256 * KVB];   // [d][32kv],  col-bytes ^= ((d>>1)&3)<<4

    const int tid  = threadIdx.x;
    const int lane = tid & 63;
    const int wid  = tid >> 6;          // 0..7 = head
    const int lc   = lane & 15;
    const int l4   = lane >> 4;

    const int bid = blockIdx.x;
    const int b   = bid >> 7;
    const int qt  = bid & 127;
    const int q0  = qt * 16;
    const int nt  = (qt >> 1) + 1;
    const int h   = wid;

    const char* QKVb = (const char*)(QKV + (size_t)(b * SEQ) * LQ);
    const char* Kg   = QKVb + 2048 * 2;
    const char* Vg   = (const char*)(Vt + (size_t)b * DH * SEQ);

    // staging constants: each wave fills 2 KB of K + 2 KB of V per tile
    const int kr0   = wid * 4 + (lane >> 5);       // +2 per i : kv row in tile
    const int kcolb = (lane & 31) * 16;            // byte col in 512B K row
    const int vd0   = wid * 32 + (lane >> 2);      // +16 per i : d row in tile
    const int vcol0 = (lane & 3) * 16;             // byte col in 64B V row
    const int vrsw  = ((lc >> 1) & 3) << 4;        // V read swizzle

#define STAGE(B_, KV0) do {                                                         \
    _Pragma("unroll")                                                               \
    for (int i_ = 0; i_ < 2; ++i_) {                                                \
        int r_ = kr0 + i_ * 2;                                                      \
        gld16(Kg + (size_t)((KV0) + r_) * (LQ * 2) + (kcolb ^ ((r_ & 7) << 4)),     \
              (char*)&Kt[B_][0] + (wid * 2 + i_) * 1024);                           \
    }                                                                               \
    _Pragma("unroll")                                                               \
    for (int i_ = 0; i_ < 2; ++i_) {                                                \
        int d_ = vd0 + i_ * 16;                                                     \
        gld16(Vg + (size_t)d_ * (SEQ * 2) + (KV0) * 2 + (vcol0 ^ (((d_ >> 1) & 3) << 4)), \
              (char*)&Vs[B_][0] + (wid * 2 + i_) * 1024);                           \
    }                                                                               \
} while (0)

    // Q fragments: col q = q0 + lc, k(d) = l4*8 + kc*32 (pre-scaled by 1/16 in rope)
    const char* Qp = QKVb + (size_t)(q0 + lc) * (LQ * 2) + h * 512 + l4 * 16;
    bf16x8 qf[8];
#pragma unroll
    for (int kc = 0; kc < 8; ++kc) qf[kc] = *(const bf16x8*)(Qp + kc * 64);

    f32x4 oacc[16];
#pragma unroll
    for (int i = 0; i < 16; ++i) oacc[i] = (f32x4)0.f;
    float mrow = -1e30f, lrow = 0.f;
    const int qrow = q0 + lc;

    STAGE(0, 0);

    int buf = 0;
    for (int t = 0; t < nt; ++t) {
        __syncthreads();                       // stage for t complete
        const int kv0 = t * KVB;
        if (t + 1 < nt) STAGE(buf ^ 1, kv0 + KVB);

        // S^T = K * Q^T : rows kv (A=K), cols q (B=Q)
        f32x4 sacc[2];
        sacc[0] = (f32x4)0.f; sacc[1] = (f32x4)0.f;
        const char* Kl = (const char*)&Kt[buf][0];
        __builtin_amdgcn_s_setprio(1);
#pragma unroll
        for (int kc = 0; kc < 8; ++kc) {
#pragma unroll
            for (int ct = 0; ct < 2; ++ct) {
                const int rr = ct * 16 + lc;
                bf16x8 kf = *(const bf16x8*)(Kl + rr * 512 +
                                             (((kc << 6) | (l4 << 4)) ^ ((rr & 7) << 4)));
                sacc[ct] = __builtin_amdgcn_mfma_f32_16x16x32_bf16(kf, qf[kc], sacc[ct], 0, 0, 0);
            }
        }
        __builtin_amdgcn_s_setprio(0);

        // online softmax over kv for column q (lane-local + 2 shfls), deferred max
        const bool lastt = (t == nt - 1);
        float tm = -1e30f;
#pragma unroll
        for (int ct = 0; ct < 2; ++ct)
#pragma unroll
            for (int r = 0; r < 4; ++r) {
                float s = sacc[ct][r];
                if (lastt) {
                    int kv = kv0 + ct * 16 + l4 * 4 + r;
                    if (kv > qrow) s = -1e30f;
                }
                sacc[ct][r] = s;
                tm = fmaxf(tm, s);
            }
        tm = fmaxf(tm, __shfl_xor(tm, 16, 64));
        tm = fmaxf(tm, __shfl_xor(tm, 32, 64));
        if (!__all(tm <= mrow + 8.f)) {
            const float mnew  = fmaxf(mrow, tm);
            const float alpha = __expf(mrow - mnew);
            mrow = mnew;
            lrow *= alpha;
#pragma unroll
            for (int dt = 0; dt < 16; ++dt) {
                oacc[dt][0] *= alpha; oacc[dt][1] *= alpha;
                oacc[dt][2] *= alpha; oacc[dt][3] *= alpha;
            }
        }
        float p0[4], p1[4], ps = 0.f;
#pragma unroll
        for (int r = 0; r < 4; ++r) { p0[r] = __expf(sacc[0][r] - mrow); ps += p0[r]; }
#pragma unroll
        for (int r = 0; r < 4; ++r) { p1[r] = __expf(sacc[1][r] - mrow); ps += p1[r]; }
        ps += __shfl_xor(ps, 16, 64);
        ps += __shfl_xor(ps, 32, 64);
        lrow += ps;

        // P^T -> PV B-frag: lane needs kv = l4*8+j at q = lc
        unsigned pkA0 = pack2bf(p0[0], p0[1]), pkA1 = pack2bf(p0[2], p0[3]);
        unsigned pkB0 = pack2bf(p1[0], p1[1]), pkB1 = pack2bf(p1[2], p1[3]);
        const int sl0 = lc + 16 * ((2 * l4) & 3);
        const int sl1 = lc + 16 * ((2 * l4 + 1) & 3);
        unsigned a0 = __shfl(pkA0, sl0, 64), a1 = __shfl(pkA1, sl0, 64);
        unsigned b0 = __shfl(pkB0, sl0, 64), b1 = __shfl(pkB1, sl0, 64);
        unsigned c0 = __shfl(pkA0, sl1, 64), c1 = __shfl(pkA1, sl1, 64);
        unsigned d0 = __shfl(pkB0, sl1, 64), d1 = __shfl(pkB1, sl1, 64);
        const bool hi = (l4 >= 2);
        union { unsigned u[4]; bf16x8 v; } pb;
        pb.u[0] = hi ? b0 : a0;
        pb.u[1] = hi ? b1 : a1;
        pb.u[2] = hi ? d0 : c0;
        pb.u[3] = hi ? d1 : c1;

        // O^T += V^T * P^T : rows d (A=V^T), cols q
        const char* Vl = (const char*)&Vs[buf][0];
        __builtin_amdgcn_s_setprio(1);
#pragma unroll
        for (int dt = 0; dt < 16; ++dt) {
            bf16x8 vf = *(const bf16x8*)(Vl + (dt * 16 + lc) * 64 + ((l4 << 4) ^ vrsw));
            oacc[dt] = __builtin_amdgcn_mfma_f32_16x16x32_bf16(vf, pb.v, oacc[dt], 0, 0, 0);
        }
        __builtin_amdgcn_s_setprio(0);
        buf ^= 1;
    }

    // epilogue: normalize + store (lane q = lc, d = dt*16 + l4*4 + r)
    const float inv = 1.f / lrow;
    char* Op = (char*)O + ((size_t)(b * SEQ + q0 + lc) * HID + h * 256 + l4 * 4) * 2;
#pragma unroll
    for (int dt = 0; dt < 16; ++dt) {
        __bf16 o4[4];
        o4[0] = (__bf16)(oacc[dt][0] * inv);
        o4[1] = (__bf16)(oacc[dt][1] * inv);
        o4[2] = (__bf16)(oacc[dt][2] * inv);
        o4[3] = (__bf16)(oacc[dt][3] * inv);
        *(uint2*)(Op + dt * 32) = *(uint2*)o4;
    }
#undef STAGE
}

extern "C" void kernel_launch(void* const* d_in, const int* in_sizes, int n_in,
                              void* d_out, int out_size, void* d_ws, size_t ws_size,
                              hipStream_t stream) {
    const float* hs  = (const float*)d_in[0];
    const int*   pid = (const int*)d_in[1];
    const float* Wq  = (const float*)d_in[3];
    const float* Wk  = (const float*)d_in[4];
    const float* Wv  = (const float*)d_in[5];
    const float* Wo  = (const float*)d_in[6];
    float* out = (float*)d_out;

    char* ws = (char*)d_ws;
    __bf16* Xb   = (__bf16*)ws;                       ws += (size_t)ROWS * HID * 2;
    __bf16* Wqkv = (__bf16*)ws;                       ws += (size_t)LQ * HID * 2;
    __bf16* Wob  = (__bf16*)ws;                       ws += (size_t)HID * HID * 2;
    __bf16* QKV  = (__bf16*)ws;                       ws += (size_t)ROWS * LQ * 2;
    __bf16* Vt   = (__bf16*)ws;                       ws += (size_t)BATCH * DH * SEQ * 2;
    __bf16* Oat  = Xb;   // alias: X dead after QKV GEMM

    cvt_f32_bf16<<<(ROWS * HID / 4 + 255) / 256, 256, 0, stream>>>(hs, Xb, ROWS * HID / 4);
    cvt_f32_bf16<<<(HID * HID / 4 + 255) / 256, 256, 0, stream>>>(Wq, Wqkv, HID * HID / 4);
    cvt_f32_bf16<<<(DH * HID / 4 + 255) / 256, 256, 0, stream>>>(Wk, Wqkv + (size_t)2048 * HID, DH * HID / 4);
    cvt_f32_bf16<<<(DH * HID / 4 + 255) / 256, 256, 0, stream>>>(Wv, Wqkv + (size_t)2304 * HID, DH * HID / 4);
    cvt_f32_bf16<<<(HID * HID / 4 + 255) / 256, 256, 0, stream>>>(Wo, Wob, HID * HID / 4);

    gemm_bt<__bf16><<<dim3(LQ / 128, ROWS / 128), 256, 0, stream>>>(Xb, Wqkv, QKV, ROWS, LQ, HID);

    rope_kernel<<<dim3(ROWS, 9), 128, 0, stream>>>(QKV, pid);

    transpose_v<<<dim3(SEQ / 32, DH / 32, BATCH), 256, 0, stream>>>(QKV, Vt);

    attn_fwd4<<<dim3(256), 512, 0, stream>>>(QKV, Vt, Oat);

    gemm_bt<float><<<dim3(HID / 128, ROWS / 128), 256, 0, stream>>>(Oat, Wob, out, ROWS, HID, HID);
}

// Round 5
// 360.573 us; speedup vs baseline: 1.1886x; 1.0914x over previous
//
#include <hip/hip_runtime.h>
#include <hip/hip_bf16.h>

typedef __bf16 bf16x8 __attribute__((ext_vector_type(8)));
typedef float  f32x4  __attribute__((ext_vector_type(4)));

#define BATCH 2
#define SEQ   2048
#define HID   2048
#define NH    8
#define DH    256
#define LQ    2560            // QKV row: 8*256 Q + 256 K + 256 V
#define ROWS  (BATCH*SEQ)     // 4096
#define KVB   32

__device__ __forceinline__ void gld16(const void* g, void* l) {
    __builtin_amdgcn_global_load_lds(
        (__attribute__((address_space(1))) void*)(g),
        (__attribute__((address_space(3))) void*)(l), 16, 0, 0);
}

__device__ __forceinline__ unsigned pack2bf(float a, float b) {
    union { __bf16 h[2]; unsigned u; } x;
    x.h[0] = (__bf16)a; x.h[1] = (__bf16)b;
    return x.u;
}

// ---------------- fp32 -> bf16 convert (vectorized) ----------------
__global__ void cvt_f32_bf16(const float* __restrict__ src, __bf16* __restrict__ dst, int n4) {
    int i = blockIdx.x * blockDim.x + threadIdx.x;
    if (i < n4) {
        float4 v = ((const float4*)src)[i];
        __bf16 o[4];
        o[0] = (__bf16)v.x; o[1] = (__bf16)v.y; o[2] = (__bf16)v.z; o[3] = (__bf16)v.w;
        ((uint2*)dst)[i] = *(uint2*)o;
    }
}

// ---------------- GEMM: C[M][N] = A[M][K] * B[N][K]^T (bf16 in, CT out) ----------------
template<typename CT>
__global__ __launch_bounds__(256)
void gemm_bt(const __bf16* __restrict__ A, const __bf16* __restrict__ B,
             CT* __restrict__ C, int M, int N, int K) {
    __shared__ __bf16 sA[128 * 32];
    __shared__ __bf16 sB[128 * 32];
    const int tid  = threadIdx.x;
    const int lane = tid & 63;
    const int wid  = tid >> 6;
    const int row0 = blockIdx.y * 128;
    const int col0 = blockIdx.x * 128;
    const int wr = (wid >> 1) * 64;
    const int wc = (wid & 1) * 64;

    const int sr0 = tid >> 2, sc0 = (tid & 3) * 8;
    const __bf16* Ag0 = A + (size_t)(row0 + sr0) * K + sc0;
    const __bf16* Ag1 = Ag0 + (size_t)64 * K;
    const __bf16* Bg0 = B + (size_t)(col0 + sr0) * K + sc0;
    const __bf16* Bg1 = Bg0 + (size_t)64 * K;
    __bf16* lA0 = &sA[wid * 512];
    __bf16* lA1 = &sA[2048 + wid * 512];
    __bf16* lB0 = &sB[wid * 512];
    __bf16* lB1 = &sB[2048 + wid * 512];

    f32x4 acc[4][4];
#pragma unroll
    for (int m = 0; m < 4; ++m)
#pragma unroll
        for (int n = 0; n < 4; ++n) acc[m][n] = (f32x4)0.f;

    for (int k0 = 0; k0 < K; k0 += 32) {
        gld16(Ag0 + k0, lA0);
        gld16(Ag1 + k0, lA1);
        gld16(Bg0 + k0, lB0);
        gld16(Bg1 + k0, lB1);
        __syncthreads();
        bf16x8 af[4], bfr[4];
#pragma unroll
        for (int m = 0; m < 4; ++m)
            af[m] = *(const bf16x8*)&sA[(wr + m * 16 + (lane & 15)) * 32 + (lane >> 4) * 8];
#pragma unroll
        for (int n = 0; n < 4; ++n)
            bfr[n] = *(const bf16x8*)&sB[(wc + n * 16 + (lane & 15)) * 32 + (lane >> 4) * 8];
#pragma unroll
        for (int m = 0; m < 4; ++m)
#pragma unroll
            for (int n = 0; n < 4; ++n)
                acc[m][n] = __builtin_amdgcn_mfma_f32_16x16x32_bf16(af[m], bfr[n], acc[m][n], 0, 0, 0);
        __syncthreads();
    }
#pragma unroll
    for (int m = 0; m < 4; ++m)
#pragma unroll
        for (int n = 0; n < 4; ++n)
#pragma unroll
            for (int r = 0; r < 4; ++r) {
                int row = row0 + wr + m * 16 + (lane >> 4) * 4 + r;
                int col = col0 + wc + n * 16 + (lane & 15);
                C[(size_t)row * N + col] = (CT)acc[m][n][r];
            }
}

// ---------------- RoPE in-place on QKV (heads 0..7 = Q scaled by 1/16, head 8 = K) --------
__global__ void rope_kernel(__bf16* __restrict__ QKV, const int* __restrict__ pid) {
    const int row = blockIdx.x;   // 0..4095
    const int h   = blockIdx.y;   // 0..8
    const int j   = threadIdx.x;  // 0..127
    const float pos = (float)pid[row];
    const float freq = exp2f((float)j * (-13.287712379549449f / 128.0f));
    const float ang = pos * freq;
    float sn, cs;
    sincosf(ang, &sn, &cs);
    const float sc = (h < 8) ? 0.0625f : 1.0f;   // fold 1/sqrt(256) into Q
    __bf16* p = QKV + (size_t)row * LQ + h * 256 + j;
    float x1 = (float)p[0], x2 = (float)p[128];
    p[0]   = (__bf16)((x1 * cs - x2 * sn) * sc);
    p[128] = (__bf16)((x2 * cs + x1 * sn) * sc);
}

// ---------------- V transpose: QKV cols 2304.. -> Vt[B][256][SEQ] ----------------
__global__ __launch_bounds__(256)
void transpose_v(const __bf16* __restrict__ QKV, __bf16* __restrict__ Vt) {
    __shared__ __bf16 t[32][33];
    const int b  = blockIdx.z;
    const int s0 = blockIdx.x * 32;
    const int d0 = blockIdx.y * 32;
    const int c  = threadIdx.x & 31;
    const int r8 = threadIdx.x >> 5;
#pragma unroll
    for (int i = 0; i < 4; ++i) {
        int row = r8 + i * 8;
        t[row][c] = QKV[(size_t)(b * SEQ + s0 + row) * LQ + 2304 + d0 + c];
    }
    __syncthreads();
#pragma unroll
    for (int i = 0; i < 4; ++i) {
        int row = r8 + i * 8;
        Vt[((size_t)b * 256 + d0 + row) * SEQ + s0 + c] = t[c][row];
    }
}

// ---------------- Flash attention v5: balanced split-kv ----------------
// 256 blocks x 512 thr (8 waves = 8 heads). Block (b, pg, kvh): processes chunk pg
// then chunk 127-pg (16 q rows each), each restricted to its kv-half -> 32/33 tiles
// per block, deterministic. Partials (unnormalized O-acc bf16 + m,l) to scratch;
// merged by merge_attn. K/V dbuf LDS staged once per tile for all 8 heads.
// Swapped QK^T -> lane-local softmax (defer-max); P to PV B-frag via per-wave LDS strip.
__global__ __launch_bounds__(512, 2)
void attn_fwd5(const __bf16* __restrict__ QKV, const __bf16* __restrict__ Vt,
               __bf16* __restrict__ A0, __bf16* __restrict__ A1,
               float2* __restrict__ ML) {
    __shared__ __bf16 Kt[2][KVB * 256];   // [kv][256d], col-bytes ^= (kv&7)<<4
    __shared__ __bf16 Vs[2][256 * KVB];   // [d][32kv],  col-bytes ^= ((d>>1)&3)<<4
    __shared__ char   Pl[8][16 * 80];     // per-wave P strip: 16 q rows x 80B (64B data)

    const int tid  = threadIdx.x;
    const int lane = tid & 63;
    const int wid  = tid >> 6;          // 0..7 = head
    const int lc   = lane & 15;
    const int l4   = lane >> 4;

    const int bid = blockIdx.x;
    const int b   = bid >> 7;
    const int pg  = bid & 63;
    const int kvh = (bid >> 6) & 1;
    const int h   = wid;

    const char* QKVb = (const char*)(QKV + (size_t)(b * SEQ) * LQ);
    const char* Kg   = QKVb + 2048 * 2;
    const char* Vg   = (const char*)(Vt + (size_t)b * DH * SEQ);

    // staging constants: each wave fills 2 KB of K + 2 KB of V per tile
    const int kr0   = wid * 4 + (lane >> 5);       // +2 per i : kv row in tile
    const int kcolb = (lane & 31) * 16;            // byte col in 512B K row
    const int vd0   = wid * 32 + (lane >> 2);      // +16 per i : d row in tile
    const int vcol0 = (lane & 3) * 16;             // byte col in 64B V row
    const int vrsw  = ((lc >> 1) & 3) << 4;        // V read swizzle
    char* Pw = &Pl[wid][0];

#define STAGE(B_, KV0) do {                                                         \
    _Pragma("unroll")                                                               \
    for (int i_ = 0; i_ < 2; ++i_) {                                                \
        int r_ = kr0 + i_ * 2;                                                      \
        gld16(Kg + (size_t)((KV0) + r_) * (LQ * 2) + (kcolb ^ ((r_ & 7) << 4)),     \
              (char*)&Kt[B_][0] + (wid * 2 + i_) * 1024);                           \
    }                                                                               \
    _Pragma("unroll")                                                               \
    for (int i_ = 0; i_ < 2; ++i_) {                                                \
        int d_ = vd0 + i_ * 16;                                                     \
        gld16(Vg + (size_t)d_ * (SEQ * 2) + (KV0) * 2 + (vcol0 ^ (((d_ >> 1) & 3) << 4)), \
              (char*)&Vs[B_][0] + (wid * 2 + i_) * 1024);                           \
    }                                                                               \
} while (0)

    for (int seg = 0; seg < 2; ++seg) {
        const int c    = seg ? (127 - pg) : pg;
        const int ntc  = (c >> 1) + 1;            // tiles this chunk needs
        const int t0   = kvh ? (ntc >> 1) : 0;    // this block's kv-half
        const int t1   = kvh ? ntc : (ntc >> 1);
        const int q0   = c * 16;
        const int qrow = q0 + lc;

        // Q fragments: col q = q0 + lc, k(d) = l4*8 + kc*32 (pre-scaled by 1/16)
        const char* Qp = QKVb + (size_t)(q0 + lc) * (LQ * 2) + h * 512 + l4 * 16;
        bf16x8 qf[8];
#pragma unroll
        for (int kc = 0; kc < 8; ++kc) qf[kc] = *(const bf16x8*)(Qp + kc * 64);

        f32x4 oacc[16];
#pragma unroll
        for (int i = 0; i < 16; ++i) oacc[i] = (f32x4)0.f;
        float mrow = -1e30f, lrow = 0.f;

        __syncthreads();   // prior segment's LDS reads done before restaging
        if (t0 < t1) {
            STAGE(0, t0 * KVB);
            int buf = 0;
            for (int t = t0; t < t1; ++t) {
                __syncthreads();                       // stage for t complete
                const int kv0 = t * KVB;
                if (t + 1 < t1) STAGE(buf ^ 1, kv0 + KVB);

                // S^T = K * Q^T : rows kv (A=K), cols q (B=Q)
                f32x4 sacc[2];
                sacc[0] = (f32x4)0.f; sacc[1] = (f32x4)0.f;
                const char* Kl = (const char*)&Kt[buf][0];
                __builtin_amdgcn_s_setprio(1);
#pragma unroll
                for (int kc = 0; kc < 8; ++kc) {
#pragma unroll
                    for (int ct = 0; ct < 2; ++ct) {
                        const int rr = ct * 16 + lc;
                        bf16x8 kf = *(const bf16x8*)(Kl + rr * 512 +
                                                     (((kc << 6) | (l4 << 4)) ^ ((rr & 7) << 4)));
                        sacc[ct] = __builtin_amdgcn_mfma_f32_16x16x32_bf16(kf, qf[kc], sacc[ct], 0, 0, 0);
                    }
                }
                __builtin_amdgcn_s_setprio(0);

                // online softmax over kv for col q (lane-local + 2 shfls), deferred max
                const bool lastt = (t == ntc - 1);
                float tm = -1e30f;
#pragma unroll
                for (int ct = 0; ct < 2; ++ct)
#pragma unroll
                    for (int r = 0; r < 4; ++r) {
                        float s = sacc[ct][r];
                        if (lastt) {
                            int kv = kv0 + ct * 16 + l4 * 4 + r;
                            if (kv > qrow) s = -1e30f;
                        }
                        sacc[ct][r] = s;
                        tm = fmaxf(tm, s);
                    }
                tm = fmaxf(tm, __shfl_xor(tm, 16, 64));
                tm = fmaxf(tm, __shfl_xor(tm, 32, 64));
                if (!__all(tm <= mrow + 8.f)) {
                    const float mnew  = fmaxf(mrow, tm);
                    const float alpha = __expf(mrow - mnew);
                    mrow = mnew;
                    lrow *= alpha;
#pragma unroll
                    for (int dt = 0; dt < 16; ++dt) {
                        oacc[dt][0] *= alpha; oacc[dt][1] *= alpha;
                        oacc[dt][2] *= alpha; oacc[dt][3] *= alpha;
                    }
                }
                float p0[4], p1[4], ps = 0.f;
#pragma unroll
                for (int r = 0; r < 4; ++r) { p0[r] = __expf(sacc[0][r] - mrow); ps += p0[r]; }
#pragma unroll
                for (int r = 0; r < 4; ++r) { p1[r] = __expf(sacc[1][r] - mrow); ps += p1[r]; }
                ps += __shfl_xor(ps, 16, 64);
                ps += __shfl_xor(ps, 32, 64);
                lrow += ps;

                // P -> per-wave LDS strip: row q=lc (80B stride), byte kv*2
                *(uint2*)(Pw + lc * 80 + l4 * 8) =
                    make_uint2(pack2bf(p0[0], p0[1]), pack2bf(p0[2], p0[3]));
                *(uint2*)(Pw + lc * 80 + 32 + l4 * 8) =
                    make_uint2(pack2bf(p1[0], p1[1]), pack2bf(p1[2], p1[3]));
                asm volatile("s_waitcnt lgkmcnt(0)" ::: "memory");
                __builtin_amdgcn_sched_barrier(0);
                // PV B-frag: q=lc, k(kv) = l4*8..+7
                bf16x8 pb = *(const bf16x8*)(Pw + lc * 80 + l4 * 16);

                // O^T += V^T * P^T : rows d (A=V^T), cols q
                const char* Vl = (const char*)&Vs[buf][0];
                __builtin_amdgcn_s_setprio(1);
#pragma unroll
                for (int dt = 0; dt < 16; ++dt) {
                    bf16x8 vf = *(const bf16x8*)(Vl + (dt * 16 + lc) * 64 + ((l4 << 4) ^ vrsw));
                    oacc[dt] = __builtin_amdgcn_mfma_f32_16x16x32_bf16(vf, pb, oacc[dt], 0, 0, 0);
                }
                __builtin_amdgcn_s_setprio(0);
                buf ^= 1;
            }
        }

        // epilogue: store RAW partial (no normalization) + (m,l)
        __bf16* dst = kvh ? A1 : A0;
        char* Op = (char*)dst + ((size_t)(b * SEQ + q0 + lc) * HID + h * 256 + l4 * 4) * 2;
#pragma unroll
        for (int dt = 0; dt < 16; ++dt) {
            __bf16 o4[4];
            o4[0] = (__bf16)oacc[dt][0];
            o4[1] = (__bf16)oacc[dt][1];
            o4[2] = (__bf16)oacc[dt][2];
            o4[3] = (__bf16)oacc[dt][3];
            *(uint2*)(Op + dt * 32) = *(uint2*)o4;
        }
        if (l4 == 0)
            ML[(size_t)kvh * ROWS * NH + (size_t)(b * SEQ + q0 + lc) * NH + h] =
                make_float2(mrow, lrow);
    }
#undef STAGE
}

// ---------------- merge the two kv-half partials: A0 = norm(w0*A0 + w1*A1) ----------
__global__ __launch_bounds__(256)
void merge_attn(__bf16* __restrict__ A0, const __bf16* __restrict__ A1,
                const float2* __restrict__ ML) {
    const int idx = blockIdx.x * 256 + threadIdx.x;   // one 8-elem group
    const int r = idx >> 8;                            // row 0..4095
    const int g = idx & 255;                           // 8-elem group in row
    const int h = g >> 5;                              // head
    const float2 ml0 = ML[(size_t)r * NH + h];
    const float2 ml1 = ML[(size_t)ROWS * NH + (size_t)r * NH + h];
    const float M  = fmaxf(ml0.x, ml1.x);
    float w0 = __expf(ml0.x - M), w1 = __expf(ml1.x - M);
    const float inv = 1.0f / (ml0.y * w0 + ml1.y * w1);
    w0 *= inv; w1 *= inv;
    const size_t off = (size_t)r * HID + (size_t)g * 8;
    bf16x8 a0 = *(const bf16x8*)(A0 + off);
    bf16x8 a1 = *(const bf16x8*)(A1 + off);
    bf16x8 o;
#pragma unroll
    for (int j = 0; j < 8; ++j)
        o[j] = (__bf16)((float)a0[j] * w0 + (float)a1[j] * w1);
    *(bf16x8*)(A0 + off) = o;
}

extern "C" void kernel_launch(void* const* d_in, const int* in_sizes, int n_in,
                              void* d_out, int out_size, void* d_ws, size_t ws_size,
                              hipStream_t stream) {
    const float* hs  = (const float*)d_in[0];
    const int*   pid = (const int*)d_in[1];
    const float* Wq  = (const float*)d_in[3];
    const float* Wk  = (const float*)d_in[4];
    const float* Wv  = (const float*)d_in[5];
    const float* Wo  = (const float*)d_in[6];
    float* out = (float*)d_out;

    char* ws = (char*)d_ws;
    __bf16* Xb    = (__bf16*)ws;                      ws += (size_t)ROWS * HID * 2;
    __bf16* Wqkv  = (__bf16*)ws;                      ws += (size_t)LQ * HID * 2;
    __bf16* Wob   = (__bf16*)ws;                      ws += (size_t)HID * HID * 2;
    __bf16* QKV   = (__bf16*)ws;                      ws += (size_t)ROWS * LQ * 2;
    __bf16* Vt    = (__bf16*)ws;                      ws += (size_t)BATCH * DH * SEQ * 2;
    __bf16* Apart = (__bf16*)ws;                      ws += (size_t)ROWS * HID * 2;
    float2* ML    = (float2*)ws;                      ws += (size_t)2 * ROWS * NH * sizeof(float2);
    __bf16* Oat   = Xb;   // alias: X dead after QKV GEMM; kvh=0 partial lands here

    cvt_f32_bf16<<<(ROWS * HID / 4 + 255) / 256, 256, 0, stream>>>(hs, Xb, ROWS * HID / 4);
    cvt_f32_bf16<<<(HID * HID / 4 + 255) / 256, 256, 0, stream>>>(Wq, Wqkv, HID * HID / 4);
    cvt_f32_bf16<<<(DH * HID / 4 + 255) / 256, 256, 0, stream>>>(Wk, Wqkv + (size_t)2048 * HID, DH * HID / 4);
    cvt_f32_bf16<<<(DH * HID / 4 + 255) / 256, 256, 0, stream>>>(Wv, Wqkv + (size_t)2304 * HID, DH * HID / 4);
    cvt_f32_bf16<<<(HID * HID / 4 + 255) / 256, 256, 0, stream>>>(Wo, Wob, HID * HID / 4);

    gemm_bt<__bf16><<<dim3(LQ / 128, ROWS / 128), 256, 0, stream>>>(Xb, Wqkv, QKV, ROWS, LQ, HID);

    rope_kernel<<<dim3(ROWS, 9), 128, 0, stream>>>(QKV, pid);

    transpose_v<<<dim3(SEQ / 32, DH / 32, BATCH), 256, 0, stream>>>(QKV, Vt);

    attn_fwd5<<<dim3(256), 512, 0, stream>>>(QKV, Vt, Oat, Apart, ML);

    merge_attn<<<dim3(ROWS * HID / 8 / 256), 256, 0, stream>>>(Oat, Apart, ML);

    gemm_bt<float><<<dim3(HID / 128, ROWS / 128), 256, 0, stream>>>(Oat, Wob, out, ROWS, HID, HID);
}

// Round 7
// 351.157 us; speedup vs baseline: 1.2205x; 1.0268x over previous
//
#include <hip/hip_runtime.h>
#include <hip/hip_bf16.h>

typedef __bf16 bf16x8 __attribute__((ext_vector_type(8)));
typedef float  f32x4  __attribute__((ext_vector_type(4)));

#define BATCH 2
#define SEQ   2048
#define HID   2048
#define NH    8
#define DH    256
#define LQ    2560            // QKV row: 8*256 Q + 256 K + 256 V
#define ROWS  (BATCH*SEQ)     // 4096
#define KVB   32

__device__ __forceinline__ void gld16(const void* g, void* l) {
    __builtin_amdgcn_global_load_lds(
        (__attribute__((address_space(1))) void*)(g),
        (__attribute__((address_space(3))) void*)(l), 16, 0, 0);
}

__device__ __forceinline__ unsigned pack2bf(float a, float b) {
    union { __bf16 h[2]; unsigned u; } x;
    x.h[0] = (__bf16)a; x.h[1] = (__bf16)b;
    return x.u;
}

// ---------------- fp32 -> bf16 convert (vectorized) ----------------
__global__ void cvt_f32_bf16(const float* __restrict__ src, __bf16* __restrict__ dst, int n4) {
    int i = blockIdx.x * blockDim.x + threadIdx.x;
    if (i < n4) {
        float4 v = ((const float4*)src)[i];
        __bf16 o[4];
        o[0] = (__bf16)v.x; o[1] = (__bf16)v.y; o[2] = (__bf16)v.z; o[3] = (__bf16)v.w;
        ((uint2*)dst)[i] = *(uint2*)o;
    }
}

// ---------------- GEMM 256x256 tile, BK=32, 4-deep pipelined counted-vmcnt ----------------
// C[M][N] = A[M][K] * B[N][K]^T (bf16 in, CT out). grid = (M/256)*(N/256) (1D, %8==0),
// 512 thr = 8 waves (2M x 4N), per-wave C = 128x64. LDS: 4 bufs x (A 16KB | B 16KB).
// LDS layout per matrix: row-pair rp (128B) of 8 16B-slots; elem(row r, k-block j) at
// slot (j + 4*(r&1)) ^ (rp&7)  -> ds_read_b128 at 2-lane/bank floor. gld16 dest linear,
// source pre-swizzled (both-sides involution). One raw s_barrier per K-tile; vmcnt(8)
// steady state (3 tiles in flight), drains only at the tail.
template<typename CT>
__global__ __launch_bounds__(512, 2)
void gemm256(const __bf16* __restrict__ A, const __bf16* __restrict__ B,
             CT* __restrict__ C, int M, int N, int K, int gn) {
    __shared__ __align__(16) char lds[4][32768];
    const int tid  = threadIdx.x;
    const int lane = tid & 63;
    const int wid  = tid >> 6;
    const int lc = lane & 15, l4 = lane >> 4;

    // bijective XCD swizzle (gridDim.x % 8 == 0)
    const int cpx = gridDim.x >> 3;
    const int wg  = (blockIdx.x & 7) * cpx + (blockIdx.x >> 3);
    const int row0 = (wg / gn) << 8;
    const int col0 = (wg % gn) << 8;

    // staging source precompute: dest slot D = i*512+tid -> (rp=D>>3, s=D&7),
    // u = s ^ (rp&7), source row r = 2*rp + (u>>2), k-block j = u&3
    int rr[2], jj[2];
#pragma unroll
    for (int i = 0; i < 2; ++i) {
        int D = i * 512 + tid, rp = D >> 3, u = (D & 7) ^ (rp & 7);
        rr[i] = (rp << 1) | (u >> 2);
        jj[i] = u & 3;
    }
    const char* As0 = (const char*)A + ((size_t)(row0 + rr[0]) * K + jj[0] * 8) * 2;
    const char* As1 = (const char*)A + ((size_t)(row0 + rr[1]) * K + jj[1] * 8) * 2;
    const char* Bs0 = (const char*)B + ((size_t)(col0 + rr[0]) * K + jj[0] * 8) * 2;
    const char* Bs1 = (const char*)B + ((size_t)(col0 + rr[1]) * K + jj[1] * 8) * 2;
    const int dst16 = tid * 16;

#define GSTAGE(bf_, tt_) do {                                   \
    size_t ko_ = (size_t)(tt_) * 64;                            \
    gld16(As0 + ko_, &lds[bf_][0]     + dst16);                 \
    gld16(As1 + ko_, &lds[bf_][8192]  + dst16);                 \
    gld16(Bs0 + ko_, &lds[bf_][16384] + dst16);                 \
    gld16(Bs1 + ko_, &lds[bf_][24576] + dst16);                 \
} while (0)

    const int wr = (wid >> 2) << 7;   // 0 / 128
    const int wc = (wid & 3) << 6;    // 0,64,128,192

    f32x4 acc[8][4];
#pragma unroll
    for (int m = 0; m < 8; ++m)
#pragma unroll
        for (int n = 0; n < 4; ++n) acc[m][n] = (f32x4)0.f;

    const int nt = K >> 5;   // K-tiles of 32
    GSTAGE(0, 0); GSTAGE(1, 1); GSTAGE(2, 2);
    asm volatile("s_waitcnt vmcnt(8)" ::: "memory");   // tile 0 landed
    __builtin_amdgcn_s_barrier();
    __builtin_amdgcn_sched_barrier(0);

    for (int t = 0; t < nt; ++t) {
        const char* Ab = &lds[t & 3][0];
        const char* Bb = &lds[t & 3][16384];
        if (t + 3 < nt) GSTAGE((t + 3) & 3, t + 3);    // issue ahead, overlaps compute

        bf16x8 af[8], bv[4];
#pragma unroll
        for (int m = 0; m < 8; ++m) {
            int r = wr + m * 16 + lc;
            af[m] = *(const bf16x8*)(Ab + (r >> 1) * 128 +
                      (((((r & 1) << 2) + l4) ^ ((r >> 1) & 7)) << 4));
        }
#pragma unroll
        for (int n = 0; n < 4; ++n) {
            int r = wc + n * 16 + lc;
            bv[n] = *(const bf16x8*)(Bb + (r >> 1) * 128 +
                      (((((r & 1) << 2) + l4) ^ ((r >> 1) & 7)) << 4));
        }
        __builtin_amdgcn_s_setprio(1);
#pragma unroll
        for (int m = 0; m < 8; ++m)
#pragma unroll
            for (int n = 0; n < 4; ++n)
                acc[m][n] = __builtin_amdgcn_mfma_f32_16x16x32_bf16(af[m], bv[n], acc[m][n], 0, 0, 0);
        __builtin_amdgcn_s_setprio(0);

        if (t + 3 < nt)      asm volatile("s_waitcnt vmcnt(8)" ::: "memory");
        else if (t + 2 < nt) asm volatile("s_waitcnt vmcnt(4)" ::: "memory");
        else if (t + 1 < nt) asm volatile("s_waitcnt vmcnt(0)" ::: "memory");
        if (t + 1 < nt) {
            __builtin_amdgcn_s_barrier();
            __builtin_amdgcn_sched_barrier(0);
        }
    }
#undef GSTAGE

    // epilogue: C row = row0+wr+m*16+l4*4+r, col = col0+wc+n*16+lc
#pragma unroll
    for (int m = 0; m < 8; ++m)
#pragma unroll
        for (int n = 0; n < 4; ++n)
#pragma unroll
            for (int r4 = 0; r4 < 4; ++r4) {
                int row = row0 + wr + m * 16 + l4 * 4 + r4;
                int col = col0 + wc + n * 16 + lc;
                C[(size_t)row * N + col] = (CT)acc[m][n][r4];
            }
}

// ---------------- RoPE in-place on QKV (heads 0..7 = Q scaled by 1/16, head 8 = K) --------
__global__ void rope_kernel(__bf16* __restrict__ QKV, const int* __restrict__ pid) {
    const int row = blockIdx.x;   // 0..4095
    const int h   = blockIdx.y;   // 0..8
    const int j   = threadIdx.x;  // 0..127
    const float pos = (float)pid[row];
    const float freq = exp2f((float)j * (-13.287712379549449f / 128.0f));
    const float ang = pos * freq;
    float sn, cs;
    sincosf(ang, &sn, &cs);
    const float sc = (h < 8) ? 0.0625f : 1.0f;   // fold 1/sqrt(256) into Q
    __bf16* p = QKV + (size_t)row * LQ + h * 256 + j;
    float x1 = (float)p[0], x2 = (float)p[128];
    p[0]   = (__bf16)((x1 * cs - x2 * sn) * sc);
    p[128] = (__bf16)((x2 * cs + x1 * sn) * sc);
}

// ---------------- V transpose: QKV cols 2304.. -> Vt[B][256][SEQ] ----------------
__global__ __launch_bounds__(256)
void transpose_v(const __bf16* __restrict__ QKV, __bf16* __restrict__ Vt) {
    __shared__ __bf16 t[32][33];
    const int b  = blockIdx.z;
    const int s0 = blockIdx.x * 32;
    const int d0 = blockIdx.y * 32;
    const int c  = threadIdx.x & 31;
    const int r8 = threadIdx.x >> 5;
#pragma unroll
    for (int i = 0; i < 4; ++i) {
        int row = r8 + i * 8;
        t[row][c] = QKV[(size_t)(b * SEQ + s0 + row) * LQ + 2304 + d0 + c];
    }
    __syncthreads();
#pragma unroll
    for (int i = 0; i < 4; ++i) {
        int row = r8 + i * 8;
        Vt[((size_t)b * 256 + d0 + row) * SEQ + s0 + c] = t[c][row];
    }
}

// ---------------- Flash attention v5: balanced split-kv ----------------
// 256 blocks x 512 thr (8 waves = 8 heads). Block (b, pg, kvh): processes chunk pg
// then chunk 127-pg (16 q rows each), each restricted to its kv-half -> 32/33 tiles
// per block, deterministic. Partials (unnormalized O-acc bf16 + m,l) to scratch;
// merged by merge_attn. K/V dbuf LDS staged once per tile for all 8 heads.
// Swapped QK^T -> lane-local softmax (defer-max); P to PV B-frag via per-wave LDS strip.
__global__ __launch_bounds__(512, 2)
void attn_fwd5(const __bf16* __restrict__ QKV, const __bf16* __restrict__ Vt,
               __bf16* __restrict__ A0, __bf16* __restrict__ A1,
               float2* __restrict__ ML) {
    __shared__ __bf16 Kt[2][KVB * 256];   // [kv][256d], col-bytes ^= (kv&7)<<4
    __shared__ __bf16 Vs[2][256 * KVB];   // [d][32kv],  col-bytes ^= ((d>>1)&3)<<4
    __shared__ char   Pl[8][16 * 80];     // per-wave P strip: 16 q rows x 80B (64B data)

    const int tid  = threadIdx.x;
    const int lane = tid & 63;
    const int wid  = tid >> 6;          // 0..7 = head
    const int lc   = lane & 15;
    const int l4   = lane >> 4;

    const int bid = blockIdx.x;
    const int b   = bid >> 7;
    const int pg  = bid & 63;
    const int kvh = (bid >> 6) & 1;
    const int h   = wid;

    const char* QKVb = (const char*)(QKV + (size_t)(b * SEQ) * LQ);
    const char* Kg   = QKVb + 2048 * 2;
    const char* Vg   = (const char*)(Vt + (size_t)b * DH * SEQ);

    // staging constants: each wave fills 2 KB of K + 2 KB of V per tile
    const int kr0   = wid * 4 + (lane >> 5);       // +2 per i : kv row in tile
    const int kcolb = (lane & 31) * 16;            // byte col in 512B K row
    const int vd0   = wid * 32 + (lane >> 2);      // +16 per i : d row in tile
    const int vcol0 = (lane & 3) * 16;             // byte col in 64B V row
    const int vrsw  = ((lc >> 1) & 3) << 4;        // V read swizzle
    char* Pw = &Pl[wid][0];

#define STAGE(B_, KV0) do {                                                         \
    _Pragma("unroll")                                                               \
    for (int i_ = 0; i_ < 2; ++i_) {                                                \
        int r_ = kr0 + i_ * 2;                                                      \
        gld16(Kg + (size_t)((KV0) + r_) * (LQ * 2) + (kcolb ^ ((r_ & 7) << 4)),     \
              (char*)&Kt[B_][0] + (wid * 2 + i_) * 1024);                           \
    }                                                                               \
    _Pragma("unroll")                                                               \
    for (int i_ = 0; i_ < 2; ++i_) {                                                \
        int d_ = vd0 + i_ * 16;                                                     \
        gld16(Vg + (size_t)d_ * (SEQ * 2) + (KV0) * 2 + (vcol0 ^ (((d_ >> 1) & 3) << 4)), \
              (char*)&Vs[B_][0] + (wid * 2 + i_) * 1024);                           \
    }                                                                               \
} while (0)

    for (int seg = 0; seg < 2; ++seg) {
        const int c    = seg ? (127 - pg) : pg;
        const int ntc  = (c >> 1) + 1;            // tiles this chunk needs
        const int t0   = kvh ? (ntc >> 1) : 0;    // this block's kv-half
        const int t1   = kvh ? ntc : (ntc >> 1);
        const int q0   = c * 16;
        const int qrow = q0 + lc;

        // Q fragments: col q = q0 + lc, k(d) = l4*8 + kc*32 (pre-scaled by 1/16)
        const char* Qp = QKVb + (size_t)(q0 + lc) * (LQ * 2) + h * 512 + l4 * 16;
        bf16x8 qf[8];
#pragma unroll
        for (int kc = 0; kc < 8; ++kc) qf[kc] = *(const bf16x8*)(Qp + kc * 64);

        f32x4 oacc[16];
#pragma unroll
        for (int i = 0; i < 16; ++i) oacc[i] = (f32x4)0.f;
        float mrow = -1e30f, lrow = 0.f;

        __syncthreads();   // prior segment's LDS reads done before restaging
        if (t0 < t1) {
            STAGE(0, t0 * KVB);
            int buf = 0;
            for (int t = t0; t < t1; ++t) {
                __syncthreads();                       // stage for t complete
                const int kv0 = t * KVB;
                if (t + 1 < t1) STAGE(buf ^ 1, kv0 + KVB);

                // S^T = K * Q^T : rows kv (A=K), cols q (B=Q)
                f32x4 sacc[2];
                sacc[0] = (f32x4)0.f; sacc[1] = (f32x4)0.f;
                const char* Kl = (const char*)&Kt[buf][0];
                __builtin_amdgcn_s_setprio(1);
#pragma unroll
                for (int kc = 0; kc < 8; ++kc) {
#pragma unroll
                    for (int ct = 0; ct < 2; ++ct) {
                        const int rr = ct * 16 + lc;
                        bf16x8 kf = *(const bf16x8*)(Kl + rr * 512 +
                                                     (((kc << 6) | (l4 << 4)) ^ ((rr & 7) << 4)));
                        sacc[ct] = __builtin_amdgcn_mfma_f32_16x16x32_bf16(kf, qf[kc], sacc[ct], 0, 0, 0);
                    }
                }
                __builtin_amdgcn_s_setprio(0);

                // online softmax over kv for col q (lane-local + 2 shfls), deferred max
                const bool lastt = (t == ntc - 1);
                float tm = -1e30f;
#pragma unroll
                for (int ct = 0; ct < 2; ++ct)
#pragma unroll
                    for (int r = 0; r < 4; ++r) {
                        float s = sacc[ct][r];
                        if (lastt) {
                            int kv = kv0 + ct * 16 + l4 * 4 + r;
                            if (kv > qrow) s = -1e30f;
                        }
                        sacc[ct][r] = s;
                        tm = fmaxf(tm, s);
                    }
                tm = fmaxf(tm, __shfl_xor(tm, 16, 64));
                tm = fmaxf(tm, __shfl_xor(tm, 32, 64));
                if (!__all(tm <= mrow + 8.f)) {
                    const float mnew  = fmaxf(mrow, tm);
                    const float alpha = __expf(mrow - mnew);
                    mrow = mnew;
                    lrow *= alpha;
#pragma unroll
                    for (int dt = 0; dt < 16; ++dt) {
                        oacc[dt][0] *= alpha; oacc[dt][1] *= alpha;
                        oacc[dt][2] *= alpha; oacc[dt][3] *= alpha;
                    }
                }
                float p0[4], p1[4], ps = 0.f;
#pragma unroll
                for (int r = 0; r < 4; ++r) { p0[r] = __expf(sacc[0][r] - mrow); ps += p0[r]; }
#pragma unroll
                for (int r = 0; r < 4; ++r) { p1[r] = __expf(sacc[1][r] - mrow); ps += p1[r]; }
                ps += __shfl_xor(ps, 16, 64);
                ps += __shfl_xor(ps, 32, 64);
                lrow += ps;

                // P -> per-wave LDS strip: row q=lc (80B stride), byte kv*2
                *(uint2*)(Pw + lc * 80 + l4 * 8) =
                    make_uint2(pack2bf(p0[0], p0[1]), pack2bf(p0[2], p0[3]));
                *(uint2*)(Pw + lc * 80 + 32 + l4 * 8) =
                    make_uint2(pack2bf(p1[0], p1[1]), pack2bf(p1[2], p1[3]));
                asm volatile("s_waitcnt lgkmcnt(0)" ::: "memory");
                __builtin_amdgcn_sched_barrier(0);
                // PV B-frag: q=lc, k(kv) = l4*8..+7
                bf16x8 pb = *(const bf16x8*)(Pw + lc * 80 + l4 * 16);

                // O^T += V^T * P^T : rows d (A=V^T), cols q
                const char* Vl = (const char*)&Vs[buf][0];
                __builtin_amdgcn_s_setprio(1);
#pragma unroll
                for (int dt = 0; dt < 16; ++dt) {
                    bf16x8 vf = *(const bf16x8*)(Vl + (dt * 16 + lc) * 64 + ((l4 << 4) ^ vrsw));
                    oacc[dt] = __builtin_amdgcn_mfma_f32_16x16x32_bf16(vf, pb, oacc[dt], 0, 0, 0);
                }
                __builtin_amdgcn_s_setprio(0);
                buf ^= 1;
            }
        }

        // epilogue: store RAW partial (no normalization) + (m,l)
        __bf16* dst = kvh ? A1 : A0;
        char* Op = (char*)dst + ((size_t)(b * SEQ + q0 + lc) * HID + h * 256 + l4 * 4) * 2;
#pragma unroll
        for (int dt = 0; dt < 16; ++dt) {
            __bf16 o4[4];
            o4[0] = (__bf16)oacc[dt][0];
            o4[1] = (__bf16)oacc[dt][1];
            o4[2] = (__bf16)oacc[dt][2];
            o4[3] = (__bf16)oacc[dt][3];
            *(uint2*)(Op + dt * 32) = *(uint2*)o4;
        }
        if (l4 == 0)
            ML[(size_t)kvh * ROWS * NH + (size_t)(b * SEQ + q0 + lc) * NH + h] =
                make_float2(mrow, lrow);
    }
#undef STAGE
}

// ---------------- merge the two kv-half partials: A0 = norm(w0*A0 + w1*A1) ----------
__global__ __launch_bounds__(256)
void merge_attn(__bf16* __restrict__ A0, const __bf16* __restrict__ A1,
                const float2* __restrict__ ML) {
    const int idx = blockIdx.x * 256 + threadIdx.x;   // one 8-elem group
    const int r = idx >> 8;                            // row 0..4095
    const int g = idx & 255;                           // 8-elem group in row
    const int h = g >> 5;                              // head
    const float2 ml0 = ML[(size_t)r * NH + h];
    const float2 ml1 = ML[(size_t)ROWS * NH + (size_t)r * NH + h];
    const float M  = fmaxf(ml0.x, ml1.x);
    float w0 = __expf(ml0.x - M), w1 = __expf(ml1.x - M);
    const float inv = 1.0f / (ml0.y * w0 + ml1.y * w1);
    w0 *= inv; w1 *= inv;
    const size_t off = (size_t)r * HID + (size_t)g * 8;
    bf16x8 a0 = *(const bf16x8*)(A0 + off);
    bf16x8 a1 = *(const bf16x8*)(A1 + off);
    bf16x8 o;
#pragma unroll
    for (int j = 0; j < 8; ++j)
        o[j] = (__bf16)((float)a0[j] * w0 + (float)a1[j] * w1);
    *(bf16x8*)(A0 + off) = o;
}

extern "C" void kernel_launch(void* const* d_in, const int* in_sizes, int n_in,
                              void* d_out, int out_size, void* d_ws, size_t ws_size,
                              hipStream_t stream) {
    const float* hs  = (const float*)d_in[0];
    const int*   pid = (const int*)d_in[1];
    const float* Wq  = (const float*)d_in[3];
    const float* Wk  = (const float*)d_in[4];
    const float* Wv  = (const float*)d_in[5];
    const float* Wo  = (const float*)d_in[6];
    float* out = (float*)d_out;

    char* ws = (char*)d_ws;
    __bf16* Xb    = (__bf16*)ws;                      ws += (size_t)ROWS * HID * 2;
    __bf16* Wqkv  = (__bf16*)ws;                      ws += (size_t)LQ * HID * 2;
    __bf16* Wob   = (__bf16*)ws;                      ws += (size_t)HID * HID * 2;
    __bf16* QKV   = (__bf16*)ws;                      ws += (size_t)ROWS * LQ * 2;
    __bf16* Vt    = (__bf16*)ws;                      ws += (size_t)BATCH * DH * SEQ * 2;
    __bf16* Apart = (__bf16*)ws;                      ws += (size_t)ROWS * HID * 2;
    float2* ML    = (float2*)ws;                      ws += (size_t)2 * ROWS * NH * sizeof(float2);
    __bf16* Oat   = Xb;   // alias: X dead after QKV GEMM; kvh=0 partial lands here

    cvt_f32_bf16<<<(ROWS * HID / 4 + 255) / 256, 256, 0, stream>>>(hs, Xb, ROWS * HID / 4);
    cvt_f32_bf16<<<(HID * HID / 4 + 255) / 256, 256, 0, stream>>>(Wq, Wqkv, HID * HID / 4);
    cvt_f32_bf16<<<(DH * HID / 4 + 255) / 256, 256, 0, stream>>>(Wk, Wqkv + (size_t)2048 * HID, DH * HID / 4);
    cvt_f32_bf16<<<(DH * HID / 4 + 255) / 256, 256, 0, stream>>>(Wv, Wqkv + (size_t)2304 * HID, DH * HID / 4);
    cvt_f32_bf16<<<(HID * HID / 4 + 255) / 256, 256, 0, stream>>>(Wo, Wob, HID * HID / 4);

    // QKV = X @ Wqkv^T : 4096 x 2560 x 2048, grid 16*10 = 160 (%8==0)
    gemm256<__bf16><<<dim3(160), 512, 0, stream>>>(Xb, Wqkv, QKV, ROWS, LQ, HID, 10);

    rope_kernel<<<dim3(ROWS, 9), 128, 0, stream>>>(QKV, pid);

    transpose_v<<<dim3(SEQ / 32, DH / 32, BATCH), 256, 0, stream>>>(QKV, Vt);

    attn_fwd5<<<dim3(256), 512, 0, stream>>>(QKV, Vt, Oat, Apart, ML);

    merge_attn<<<dim3(ROWS * HID / 8 / 256), 256, 0, stream>>>(Oat, Apart, ML);

    // out = Oat @ Wo^T : 4096 x 2048 x 2048, grid 16*8 = 128 (%8==0)
    gemm256<float><<<dim3(128), 512, 0, stream>>>(Oat, Wob, out, ROWS, HID, HID, 8);
}